// Round 5
// baseline (905.875 us; speedup 1.0000x reference)
//
#include <hip/hip_runtime.h>

#define DD 128
#define K2 256     // concatenated K: [msg | ego*msg]
#define NBMAX 1024 // max bucket count (N/128)
#define COLMASK 0x01FFFFFF

typedef short short8 __attribute__((ext_vector_type(8)));
typedef float f32x4  __attribute__((ext_vector_type(4)));

static inline size_t align256(size_t x){ return (x + 255) & ~(size_t)255; }

__device__ __forceinline__ unsigned short f2bf(float x){
  unsigned int u = __builtin_bit_cast(unsigned int, x);
  u += 0x7fff + ((u >> 16) & 1);          // RNE fp32 -> bf16
  return (unsigned short)(u >> 16);
}
__device__ __forceinline__ float bf2f(unsigned short h){
  unsigned int u = ((unsigned int)h) << 16;
  return __builtin_bit_cast(float, u);
}

// ---------------- utility ----------------
__global__ void zero_i32_kernel(int* __restrict__ p, int n){
  int i = blockIdx.x*blockDim.x + threadIdx.x;
  if (i < n) p[i] = 0;
}

// emb fp32 -> bf16 (packed 2/uint)
__global__ void cvt_bf16_kernel(const float* __restrict__ src, unsigned int* __restrict__ dst, int n2){
  int i = blockIdx.x*blockDim.x + threadIdx.x;
  if (i < n2){
    float2 v = *(const float2*)(src + (size_t)i*2);
    dst[i] = (unsigned int)f2bf(v.x) | ((unsigned int)f2bf(v.y) << 16);
  }
}

// ---------------- CSR build: degree + rowptr scan ----------------
__global__ void degree_kernel(const int* __restrict__ row, int E, int* __restrict__ deg){
  int e = blockIdx.x*blockDim.x + threadIdx.x;
  if (e < E) atomicAdd(&deg[row[e]], 1);
}

__global__ void chunk_sum_kernel(const int* __restrict__ deg, int N, int* __restrict__ csum){
  __shared__ int sh[256];
  int t = threadIdx.x;
  int base = blockIdx.x*1024;
  int s = 0;
  for (int i = t; i < 1024; i += 256){
    int idx = base + i;
    if (idx < N) s += deg[idx];
  }
  sh[t] = s; __syncthreads();
  for (int o = 128; o > 0; o >>= 1){
    if (t < o) sh[t] += sh[t+o];
    __syncthreads();
  }
  if (t == 0) csum[blockIdx.x] = sh[0];
}

__global__ void chunk_scan_kernel(int* __restrict__ csum, int C, int* __restrict__ total){
  if (blockIdx.x == 0 && threadIdx.x == 0){
    int run = 0;
    for (int i = 0; i < C; i++){ int v = csum[i]; csum[i] = run; run += v; }
    *total = run;
  }
}

__global__ void scan_within_kernel(const int* __restrict__ deg, int N,
                                   const int* __restrict__ csum, int* __restrict__ rowptr){
  __shared__ int a[256], b[256];
  int t = threadIdx.x;
  int base = blockIdx.x*1024 + t*4;
  int v[4]; int s = 0;
#pragma unroll
  for (int i = 0; i < 4; i++){
    int idx = base + i;
    int d = (idx < N) ? deg[idx] : 0;
    v[i] = s; s += d;
  }
  a[t] = s; __syncthreads();
  int* src = a; int* dst = b;
  for (int o = 1; o < 256; o <<= 1){
    int val = src[t];
    if (t >= o) val += src[t - o];
    dst[t] = val;
    __syncthreads();
    int* tmp = src; src = dst; dst = tmp;
  }
  int excl = (t == 0) ? 0 : src[t-1];
  int off = csum[blockIdx.x] + excl;
#pragma unroll
  for (int i = 0; i < 4; i++){
    int idx = base + i;
    if (idx < N) rowptr[idx] = off + v[i];
  }
}

// ---------------- binned fill, phase A: append into bucket regions ----------------
__global__ void bcur_init_kernel(const int* __restrict__ rowptr, int* __restrict__ bcur,
                                 int NB, int N){
  int b = blockIdx.x*blockDim.x + threadIdx.x;
  if (b < NB){
    int rr = b*128; if (rr > N) rr = N;
    bcur[b] = rowptr[rr];
  }
}

__global__ __launch_bounds__(256) void fill_binned_kernel(
    const int* __restrict__ ei, const float* __restrict__ ew, int E,
    int* __restrict__ bcur, int2* __restrict__ csre, int NB){
  __shared__ int lhist[NBMAX];
  __shared__ int lbase[NBMAX];
  int t = threadIdx.x;
  int base = blockIdx.x * 4096;
  for (int j = t; j < NB; j += 256) lhist[j] = 0;
  __syncthreads();
  int rows[16];
#pragma unroll
  for (int i = 0; i < 16; i++){
    int e = base + i*256 + t;
    int r = (e < E) ? ei[e] : -1;
    rows[i] = r;
    if (r >= 0) atomicAdd(&lhist[r >> 7], 1);
  }
  __syncthreads();
  for (int j = t; j < NB; j += 256){
    int c = lhist[j];
    lbase[j] = c ? atomicAdd(&bcur[j], c) : 0;
    lhist[j] = 0;                     // reuse as local cursor
  }
  __syncthreads();
#pragma unroll
  for (int i = 0; i < 16; i++){
    int e = base + i*256 + t;
    int r = rows[i];
    if (r >= 0){
      int b = r >> 7;
      int pos = lbase[b] + atomicAdd(&lhist[b], 1);
      int col = ei[E + e];
      float w = ew[e];
      csre[pos] = make_int2(((r & 127) << 25) | col, __float_as_int(w));
    }
  }
}

// ---------------- binned fill, phase B: rank by row within bucket -> exact CSR ----------------
__global__ __launch_bounds__(256) void sortbkt_kernel(
    const int* __restrict__ rowptr, const int2* __restrict__ csre,
    int2* __restrict__ csre2, int N){
  __shared__ int lrp[129];
  __shared__ int lcur[128];
  int b = blockIdx.x;
  int t = threadIdx.x;
  int r0 = b*128;
  for (int j = t; j < 129; j += 256){
    int rr = r0 + j; if (rr > N) rr = N;
    lrp[j] = rowptr[rr];
  }
  if (t < 128) lcur[t] = 0;
  __syncthreads();
  int beg = lrp[0], end = lrp[128];
  for (int i = beg + t; i < end; i += 256){
    int2 e = csre[i];
    int rl = ((unsigned int)e.x) >> 25;
    int pos = lrp[rl] + atomicAdd(&lcur[rl], 1);
    csre2[pos] = e;                   // scattered only within ~16 KB window
  }
}

// ---------------- weight pack: wb[l][n][k2] bf16 ----------------
__global__ void pack_wb_kernel(const float* __restrict__ gcw, const float* __restrict__ biw,
                               unsigned short* __restrict__ wb, int LYR){
  int i = blockIdx.x*blockDim.x + threadIdx.x;
  int total = LYR*DD*K2;
  if (i >= total) return;
  int l = i / (DD*K2);
  int r = i - l*(DD*K2);
  int n = r >> 8;
  int k = r & (K2-1);
  float v = (k < DD) ? gcw[(size_t)l*DD*DD + n*DD + k]
                     : biw[(size_t)l*DD*DD + n*DD + (k - DD)];
  wb[i] = f2bf(v);
}

// ---------------- fused layer: gather + MFMA transform + norm-scale ----------------
// Per 64-row tile: phase 1 gathers msg rows (random bf16 row reads) and builds the
// [msg | bf16(msg)*ego] A-tile in LDS; phase 2 does the K=256 bf16 MFMA GEMM; phase 3
// applies bias+leaky_relu, writes bf16 features (ping-pong buffer) and 1/||row||.
__global__ __launch_bounds__(256) void layer_fused_kernel(
    const int* __restrict__ rowptr, const int2* __restrict__ csre,
    const unsigned short* __restrict__ egoh_in,   // N x 128 bf16 (read-only this layer)
    const unsigned short* __restrict__ wb,        // 128 x 256 bf16 packed weights
    const float* __restrict__ gcb, const float* __restrict__ bib,
    unsigned short* __restrict__ egoh_out,        // N x 128 bf16 (ping-pong)
    float* __restrict__ nscale, int N){
  __shared__ unsigned short As[64*264];   // 64 rows x (256+8 pad)
  __shared__ float Bias[DD];
  int t = threadIdx.x;
  int wave = t >> 6, lane = t & 63;
  int r0 = blockIdx.x * 64;
  if (t < DD) Bias[t] = gcb[t] + bib[t];

  // ---- phase 1: gather 16 rows per wave ----
  for (int i = 0; i < 16; i++){
    int rl = wave*16 + i;
    int gr = r0 + rl;
    float ax = 0.f, ay = 0.f;
    unsigned int ev = 0;
    if (gr < N){
      int beg = rowptr[gr], end = rowptr[gr+1];
      int k = beg;
      for (; k + 8 <= end; k += 8){
        int2 e[8]; unsigned int v[8];
#pragma unroll
        for (int u = 0; u < 8; u++) e[u] = csre[k+u];
#pragma unroll
        for (int u = 0; u < 8; u++)
          v[u] = *(const unsigned int*)(egoh_in + (size_t)(e[u].x & COLMASK)*DD + lane*2);
#pragma unroll
        for (int u = 0; u < 8; u++){
          float w = __int_as_float(e[u].y);
          ax = fmaf(w, bf2f((unsigned short)v[u]), ax);
          ay = fmaf(w, bf2f((unsigned short)(v[u]>>16)), ay);
        }
      }
      for (; k < end; k++){
        int2 e = csre[k];
        unsigned int v = *(const unsigned int*)(egoh_in + (size_t)(e.x & COLMASK)*DD + lane*2);
        float w = __int_as_float(e.y);
        ax = fmaf(w, bf2f((unsigned short)v), ax);
        ay = fmaf(w, bf2f((unsigned short)(v>>16)), ay);
      }
      ev = *(const unsigned int*)(egoh_in + (size_t)gr*DD + lane*2);
    }
    unsigned short mx = f2bf(ax), my = f2bf(ay);
    float px = bf2f(mx) * bf2f((unsigned short)ev);        // bf16(msg) * bf16(ego)
    float py = bf2f(my) * bf2f((unsigned short)(ev>>16));
    *(unsigned int*)&As[rl*264 + lane*2]      = (unsigned int)mx | ((unsigned int)my << 16);
    *(unsigned int*)&As[rl*264 + DD + lane*2] = (unsigned int)f2bf(px) | ((unsigned int)f2bf(py) << 16);
  }
  __syncthreads();

  // ---- phase 2: MFMA; wave computes its own 16 rows x 128 cols ----
  int m = lane & 15, q = lane >> 4;
  f32x4 acc[8];
#pragma unroll
  for (int ct = 0; ct < 8; ct++) acc[ct] = (f32x4)0.f;

#pragma unroll
  for (int kc = 0; kc < 8; kc++){
    int koff = kc*32 + q*8;
    short8 a0 = *(const short8*)&As[(wave*16 + m)*264 + koff];
#pragma unroll
    for (int ct = 0; ct < 8; ct++){
      short8 b = *(const short8*)&wb[(size_t)(ct*16 + m)*K2 + koff];
      acc[ct] = __builtin_amdgcn_mfma_f32_16x16x32_bf16(a0, b, acc[ct], 0, 0, 0);
    }
  }

  // ---- phase 3: epilogue (row = r0 + wave*16 + q*4 + reg) ----
#pragma unroll
  for (int reg = 0; reg < 4; reg++){
    int gr = r0 + wave*16 + q*4 + reg;
    float rs = 0.f;
#pragma unroll
    for (int ct = 0; ct < 8; ct++){
      float x = acc[ct][reg] + Bias[ct*16 + m];
      x = (x > 0.f) ? x : 0.2f*x;
      rs += x*x;
      if (gr < N) egoh_out[(size_t)gr*DD + ct*16 + m] = f2bf(x);
    }
#pragma unroll
    for (int o = 1; o < 16; o <<= 1) rs += __shfl_xor(rs, o, 16);
    if (m == 0 && gr < N)
      nscale[gr] = 1.0f / fmaxf(sqrtf(rs), 1e-12f);
  }
}

// ---------------- score ----------------
__global__ void score_kernel(const int* __restrict__ eli, int Q,
                             const unsigned short* __restrict__ feath,
                             const float* __restrict__ nscale,
                             float* __restrict__ out, int accumulate){
  int wid = (int)(((size_t)blockIdx.x*blockDim.x + threadIdx.x) >> 6);
  int lane = threadIdx.x & 63;
  if (wid >= Q) return;
  int s = eli[wid];
  int d = eli[Q + wid];
  unsigned int a = *(const unsigned int*)(feath + (size_t)s*DD + lane*2);
  unsigned int b = *(const unsigned int*)(feath + (size_t)d*DD + lane*2);
  float p = bf2f((unsigned short)a)*bf2f((unsigned short)b)
          + bf2f((unsigned short)(a>>16))*bf2f((unsigned short)(b>>16));
  for (int o = 32; o > 0; o >>= 1) p += __shfl_xor(p, o, 64);
  if (lane == 0){
    if (nscale) p *= nscale[s]*nscale[d];
    if (accumulate) out[wid] += p;
    else            out[wid]  = p;
  }
}

extern "C" void kernel_launch(void* const* d_in, const int* in_sizes, int n_in,
                              void* d_out, int out_size, void* d_ws, size_t ws_size,
                              hipStream_t stream){
  const int*   edge_index = (const int*)d_in[0];
  const int*   eli        = (const int*)d_in[1];
  const float* ew         = (const float*)d_in[2];
  const float* emb        = (const float*)d_in[3];
  const float* gcw        = (const float*)d_in[4];
  const float* gcb        = (const float*)d_in[5];
  const float* biw        = (const float*)d_in[6];
  const float* bib        = (const float*)d_in[7];
  const int E   = in_sizes[2];
  const int Q   = in_sizes[1] / 2;
  const int N   = in_sizes[3] / DD;
  const int LYR = in_sizes[4] / (DD*DD);
  float* out = (float*)d_out;

  char* base = (char*)d_ws;
  size_t off = 0;
  auto carve = [&](size_t bytes)->char*{
    char* r = base + off;
    off = align256(off + bytes);
    return r;
  };
  unsigned short* featA  = (unsigned short*) carve((size_t)N*DD*sizeof(unsigned short));
  unsigned short* featB  = (unsigned short*) carve((size_t)N*DD*sizeof(unsigned short));
  unsigned short* wb     = (unsigned short*) carve((size_t)LYR*DD*K2*sizeof(unsigned short));
  float*          nscale = (float*)          carve((size_t)N*sizeof(float));
  int*            rowptr = (int*)            carve((size_t)(N+1)*sizeof(int));
  int*            deg    = (int*)            carve((size_t)N*sizeof(int));
  int*            bcur   = (int*)            carve((size_t)NBMAX*sizeof(int));
  int*            csum   = (int*)            carve(4096);
  int2*           csre   = (int2*)           carve((size_t)E*sizeof(int2));
  int2*           csre2  = (int2*)           carve((size_t)E*sizeof(int2));
  (void)ws_size; (void)n_in; (void)out_size;

  const int C  = (N + 1023)/1024;
  const int NB = (N + 127)/128;

  // CSR build (rowptr) + binned fill + packs
  zero_i32_kernel<<<(N + 255)/256, 256, 0, stream>>>(deg, N);
  degree_kernel<<<(E + 255)/256, 256, 0, stream>>>(edge_index, E, deg);
  chunk_sum_kernel<<<C, 256, 0, stream>>>(deg, N, csum);
  chunk_scan_kernel<<<1, 64, 0, stream>>>(csum, C, rowptr + N);
  scan_within_kernel<<<C, 256, 0, stream>>>(deg, N, csum, rowptr);
  bcur_init_kernel<<<(NB + 255)/256, 256, 0, stream>>>(rowptr, bcur, NB, N);
  fill_binned_kernel<<<(E + 4095)/4096, 256, 0, stream>>>(edge_index, ew, E, bcur, csre, NB);
  sortbkt_kernel<<<NB, 256, 0, stream>>>(rowptr, csre, csre2, N);
  pack_wb_kernel<<<(LYR*DD*K2 + 255)/256, 256, 0, stream>>>(gcw, biw, wb, LYR);
  cvt_bf16_kernel<<<((N*DD/2) + 255)/256, 256, 0, stream>>>(emb, (unsigned int*)featA, N*DD/2);

  // stage 0: raw emb dot (bf16 copy)
  {
    int blocks = (int)(((size_t)Q*64 + 255)/256);
    score_kernel<<<blocks, 256, 0, stream>>>(eli, Q, featA, (const float*)nullptr, out, 0);
  }

  unsigned short* cursrc = featA;
  unsigned short* curdst = featB;
  for (int l = 0; l < LYR; l++){
    layer_fused_kernel<<<(N + 63)/64, 256, 0, stream>>>(
        rowptr, csre2, cursrc, wb + (size_t)l*DD*K2,
        gcb + (size_t)l*DD, bib + (size_t)l*DD, curdst, nscale, N);
    {
      int blocks = (int)(((size_t)Q*64 + 255)/256);
      score_kernel<<<blocks, 256, 0, stream>>>(eli, Q, curdst, nscale, out, 1);
    }
    unsigned short* tmp = cursrc; cursrc = curdst; curdst = tmp;
  }
}

// Round 6
// 672.089 us; speedup vs baseline: 1.3478x; 1.3478x over previous
//
#include <hip/hip_runtime.h>

#define DD 128
#define K2 256     // concatenated K: [msg | ego*msg]
#define NBMAX 1024 // max bucket count (N/128)
#define COLMASK 0x01FFFFFF

typedef short short8 __attribute__((ext_vector_type(8)));
typedef float f32x4  __attribute__((ext_vector_type(4)));

static inline size_t align256(size_t x){ return (x + 255) & ~(size_t)255; }

__device__ __forceinline__ unsigned short f2bf(float x){
  unsigned int u = __builtin_bit_cast(unsigned int, x);
  u += 0x7fff + ((u >> 16) & 1);          // RNE fp32 -> bf16
  return (unsigned short)(u >> 16);
}
__device__ __forceinline__ float bf2f(unsigned short h){
  unsigned int u = ((unsigned int)h) << 16;
  return __builtin_bit_cast(float, u);
}

// ---------------- utility ----------------
__global__ void zero_i32_kernel(int* __restrict__ p, int n){
  int i = blockIdx.x*blockDim.x + threadIdx.x;
  if (i < n) p[i] = 0;
}

// emb fp32 -> bf16 (packed 2/uint)
__global__ void cvt_bf16_kernel(const float* __restrict__ src, unsigned int* __restrict__ dst, int n2){
  int i = blockIdx.x*blockDim.x + threadIdx.x;
  if (i < n2){
    float2 v = *(const float2*)(src + (size_t)i*2);
    dst[i] = (unsigned int)f2bf(v.x) | ((unsigned int)f2bf(v.y) << 16);
  }
}

// ---------------- CSR build: degree + PADDED rowptr scan (rows padded to x8) ----------------
__global__ void degree_kernel(const int* __restrict__ row, int E, int* __restrict__ deg){
  int e = blockIdx.x*blockDim.x + threadIdx.x;
  if (e < E) atomicAdd(&deg[row[e]], 1);
}

__global__ void chunk_sum_kernel(const int* __restrict__ deg, int N, int* __restrict__ csum){
  __shared__ int sh[256];
  int t = threadIdx.x;
  int base = blockIdx.x*1024;
  int s = 0;
  for (int i = t; i < 1024; i += 256){
    int idx = base + i;
    if (idx < N) s += (deg[idx] + 7) & ~7;      // padded degree
  }
  sh[t] = s; __syncthreads();
  for (int o = 128; o > 0; o >>= 1){
    if (t < o) sh[t] += sh[t+o];
    __syncthreads();
  }
  if (t == 0) csum[blockIdx.x] = sh[0];
}

__global__ void chunk_scan_kernel(int* __restrict__ csum, int C, int* __restrict__ total){
  if (blockIdx.x == 0 && threadIdx.x == 0){
    int run = 0;
    for (int i = 0; i < C; i++){ int v = csum[i]; csum[i] = run; run += v; }
    *total = run;
  }
}

__global__ void scan_within_kernel(const int* __restrict__ deg, int N,
                                   const int* __restrict__ csum, int* __restrict__ rowptr){
  __shared__ int a[256], b[256];
  int t = threadIdx.x;
  int base = blockIdx.x*1024 + t*4;
  int v[4]; int s = 0;
#pragma unroll
  for (int i = 0; i < 4; i++){
    int idx = base + i;
    int d = (idx < N) ? ((deg[idx] + 7) & ~7) : 0;   // padded degree
    v[i] = s; s += d;
  }
  a[t] = s; __syncthreads();
  int* src = a; int* dst = b;
  for (int o = 1; o < 256; o <<= 1){
    int val = src[t];
    if (t >= o) val += src[t - o];
    dst[t] = val;
    __syncthreads();
    int* tmp = src; src = dst; dst = tmp;
  }
  int excl = (t == 0) ? 0 : src[t-1];
  int off = csum[blockIdx.x] + excl;
#pragma unroll
  for (int i = 0; i < 4; i++){
    int idx = base + i;
    if (idx < N) rowptr[idx] = off + v[i];
  }
}

// ---------------- binned fill, phase A: append into bucket regions ----------------
__global__ void bcur_init_kernel(const int* __restrict__ rowptr, int* __restrict__ bcur,
                                 int NB, int N){
  int b = blockIdx.x*blockDim.x + threadIdx.x;
  if (b < NB){
    int rr = b*128; if (rr > N) rr = N;
    bcur[b] = rowptr[rr];
  }
}

__global__ __launch_bounds__(256) void fill_binned_kernel(
    const int* __restrict__ ei, const float* __restrict__ ew, int E,
    int* __restrict__ bcur, int2* __restrict__ csre, int NB){
  __shared__ int lhist[NBMAX];
  __shared__ int lbase[NBMAX];
  int t = threadIdx.x;
  int base = blockIdx.x * 4096;
  for (int j = t; j < NB; j += 256) lhist[j] = 0;
  __syncthreads();
  int rows[16];
#pragma unroll
  for (int i = 0; i < 16; i++){
    int e = base + i*256 + t;
    int r = (e < E) ? ei[e] : -1;
    rows[i] = r;
    if (r >= 0) atomicAdd(&lhist[r >> 7], 1);
  }
  __syncthreads();
  for (int j = t; j < NB; j += 256){
    int c = lhist[j];
    lbase[j] = c ? atomicAdd(&bcur[j], c) : 0;
    lhist[j] = 0;                     // reuse as local cursor
  }
  __syncthreads();
#pragma unroll
  for (int i = 0; i < 16; i++){
    int e = base + i*256 + t;
    int r = rows[i];
    if (r >= 0){
      int b = r >> 7;
      int pos = lbase[b] + atomicAdd(&lhist[b], 1);
      int col = ei[E + e];
      float w = ew[e];
      csre[pos] = make_int2(((r & 127) << 25) | col, __float_as_int(w));
    }
  }
}

// ---------------- binned fill, phase B: rank by row within bucket -> padded CSR ----------------
// bcur[b] (post phase A) = end of the bucket's real edges.  After placement, each
// row r pads [rowptr[r]+deg, rowptr[r+1]) with (col=r, w=0) so gather is tail-free.
__global__ __launch_bounds__(256) void sortbkt_kernel(
    const int* __restrict__ rowptr, const int* __restrict__ bcur,
    const int2* __restrict__ csre, int2* __restrict__ csre2, int N){
  __shared__ int lrp[129];
  __shared__ int lcur[128];
  int b = blockIdx.x;
  int t = threadIdx.x;
  int r0 = b*128;
  for (int j = t; j < 129; j += 256){
    int rr = r0 + j; if (rr > N) rr = N;
    lrp[j] = rowptr[rr];
  }
  if (t < 128) lcur[t] = 0;
  __syncthreads();
  int beg = lrp[0], bend = bcur[b];
  for (int i = beg + t; i < bend; i += 256){
    int2 e = csre[i];
    int rl = ((unsigned int)e.x) >> 25;
    int pos = lrp[rl] + atomicAdd(&lcur[rl], 1);
    csre2[pos] = e;                   // scattered only within ~16 KB window
  }
  __syncthreads();
  if (t < 128 && r0 + t < N){
    int pbeg = lrp[t] + lcur[t];      // after real edges
    int pend = lrp[t+1];              // padded row end
    int2 pad = make_int2(r0 + t, 0);  // w = 0 -> contributes nothing
    for (int i = pbeg; i < pend; i++) csre2[i] = pad;
  }
}

// ---------------- weight pack: wb[l][n][k2] bf16 ----------------
__global__ void pack_wb_kernel(const float* __restrict__ gcw, const float* __restrict__ biw,
                               unsigned short* __restrict__ wb, int LYR){
  int i = blockIdx.x*blockDim.x + threadIdx.x;
  int total = LYR*DD*K2;
  if (i >= total) return;
  int l = i / (DD*K2);
  int r = i - l*(DD*K2);
  int n = r >> 8;
  int k = r & (K2-1);
  float v = (k < DD) ? gcw[(size_t)l*DD*DD + n*DD + k]
                     : biw[(size_t)l*DD*DD + n*DD + (k - DD)];
  wb[i] = f2bf(v);
}

// ---------------- gather: msgh[n] = bf16( sum_e w*egoh[col] ), tail-free (rows padded x8) ----
__global__ void gather_kernel(const int* __restrict__ rowptr, const int2* __restrict__ csre,
                              const unsigned short* __restrict__ egoh,
                              unsigned int* __restrict__ msgh, int N){
  int wid = (int)(((size_t)blockIdx.x*blockDim.x + threadIdx.x) >> 6);
  int lane = threadIdx.x & 63;
  if (wid >= N) return;
  int beg = rowptr[wid], end = rowptr[wid+1];
  float ax = 0.f, ay = 0.f;
  for (int k = beg; k < end; k += 8){   // always full batches of 8
    int2 e[8]; unsigned int v[8];
#pragma unroll
    for (int u = 0; u < 8; u++) e[u] = csre[k+u];
#pragma unroll
    for (int u = 0; u < 8; u++)
      v[u] = *(const unsigned int*)(egoh + (size_t)(e[u].x & COLMASK)*DD + lane*2);
#pragma unroll
    for (int u = 0; u < 8; u++){
      float w = __int_as_float(e[u].y);
      ax = fmaf(w, bf2f((unsigned short)v[u]), ax);
      ay = fmaf(w, bf2f((unsigned short)(v[u]>>16)), ay);
    }
  }
  msgh[(size_t)wid*(DD/2) + lane] = (unsigned int)f2bf(ax) | ((unsigned int)f2bf(ay) << 16);
}

// ---------------- transform (bf16 MFMA, K=256 concat GEMM), all-bf16 I/O ----------------
__global__ __launch_bounds__(128) void transform_mfma_kernel(
    const unsigned short* __restrict__ egoh_in, const unsigned short* __restrict__ msgh,
    const unsigned short* __restrict__ wb, const float* __restrict__ gcb,
    const float* __restrict__ bib, unsigned short* __restrict__ egoh_out,
    float* __restrict__ nscale, int N){
  __shared__ unsigned short As[64*264];
  __shared__ float Bias[DD];
  int t = threadIdx.x;
  int r0 = blockIdx.x * 64;
  if (t < DD) Bias[t] = gcb[t] + bib[t];

#pragma unroll
  for (int it = 0; it < 8; it++){
    int i = it*128 + t;
    int r = i >> 4, c = (i & 15);
    int gr = r0 + r;
    uint4 m4 = make_uint4(0,0,0,0), e4 = make_uint4(0,0,0,0);
    if (gr < N){
      m4 = *(const uint4*)(msgh    + (size_t)gr*DD + c*8);
      e4 = *(const uint4*)(egoh_in + (size_t)gr*DD + c*8);
    }
    *(uint4*)&As[r*264 + c*8] = m4;
    unsigned int p[4];
    unsigned int me[4] = {m4.x, m4.y, m4.z, m4.w};
    unsigned int ee[4] = {e4.x, e4.y, e4.z, e4.w};
#pragma unroll
    for (int u = 0; u < 4; u++){
      float px = bf2f((unsigned short)me[u]) * bf2f((unsigned short)ee[u]);
      float py = bf2f((unsigned short)(me[u]>>16)) * bf2f((unsigned short)(ee[u]>>16));
      p[u] = (unsigned int)f2bf(px) | ((unsigned int)f2bf(py) << 16);
    }
    *(uint4*)&As[r*264 + DD + c*8] = make_uint4(p[0],p[1],p[2],p[3]);
  }
  __syncthreads();

  int wave = t >> 6, lane = t & 63;
  int m = lane & 15, q = lane >> 4;
  int wr0 = wave * 32;

  f32x4 acc[8][2];
#pragma unroll
  for (int ct = 0; ct < 8; ct++){ acc[ct][0] = (f32x4)0.f; acc[ct][1] = (f32x4)0.f; }

#pragma unroll
  for (int kc = 0; kc < 8; kc++){
    int koff = kc*32 + q*8;
    short8 a0 = *(const short8*)&As[(wr0 + m)*264 + koff];
    short8 a1 = *(const short8*)&As[(wr0 + 16 + m)*264 + koff];
#pragma unroll
    for (int ct = 0; ct < 8; ct++){
      short8 b = *(const short8*)&wb[(size_t)(ct*16 + m)*K2 + koff];
      acc[ct][0] = __builtin_amdgcn_mfma_f32_16x16x32_bf16(a0, b, acc[ct][0], 0, 0, 0);
      acc[ct][1] = __builtin_amdgcn_mfma_f32_16x16x32_bf16(a1, b, acc[ct][1], 0, 0, 0);
    }
  }

#pragma unroll
  for (int rt = 0; rt < 2; rt++){
#pragma unroll
    for (int reg = 0; reg < 4; reg++){
      int gr = r0 + wr0 + rt*16 + q*4 + reg;
      float rs = 0.f;
#pragma unroll
      for (int ct = 0; ct < 8; ct++){
        float x = acc[ct][rt][reg] + Bias[ct*16 + m];
        x = (x > 0.f) ? x : 0.2f*x;
        rs += x*x;
        if (gr < N) egoh_out[(size_t)gr*DD + ct*16 + m] = f2bf(x);
      }
#pragma unroll
      for (int o = 1; o < 16; o <<= 1) rs += __shfl_xor(rs, o, 16);
      if (m == 0 && gr < N)
        nscale[gr] = 1.0f / fmaxf(sqrtf(rs), 1e-12f);
    }
  }
}

// ---------------- score ----------------
__global__ void score_kernel(const int* __restrict__ eli, int Q,
                             const unsigned short* __restrict__ feath,
                             const float* __restrict__ nscale,
                             float* __restrict__ out, int accumulate){
  int wid = (int)(((size_t)blockIdx.x*blockDim.x + threadIdx.x) >> 6);
  int lane = threadIdx.x & 63;
  if (wid >= Q) return;
  int s = eli[wid];
  int d = eli[Q + wid];
  unsigned int a = *(const unsigned int*)(feath + (size_t)s*DD + lane*2);
  unsigned int b = *(const unsigned int*)(feath + (size_t)d*DD + lane*2);
  float p = bf2f((unsigned short)a)*bf2f((unsigned short)b)
          + bf2f((unsigned short)(a>>16))*bf2f((unsigned short)(b>>16));
  for (int o = 32; o > 0; o >>= 1) p += __shfl_xor(p, o, 64);
  if (lane == 0){
    if (nscale) p *= nscale[s]*nscale[d];
    if (accumulate) out[wid] += p;
    else            out[wid]  = p;
  }
}

extern "C" void kernel_launch(void* const* d_in, const int* in_sizes, int n_in,
                              void* d_out, int out_size, void* d_ws, size_t ws_size,
                              hipStream_t stream){
  const int*   edge_index = (const int*)d_in[0];
  const int*   eli        = (const int*)d_in[1];
  const float* ew         = (const float*)d_in[2];
  const float* emb        = (const float*)d_in[3];
  const float* gcw        = (const float*)d_in[4];
  const float* gcb        = (const float*)d_in[5];
  const float* biw        = (const float*)d_in[6];
  const float* bib        = (const float*)d_in[7];
  const int E   = in_sizes[2];
  const int Q   = in_sizes[1] / 2;
  const int N   = in_sizes[3] / DD;
  const int LYR = in_sizes[4] / (DD*DD);
  float* out = (float*)d_out;

  char* base = (char*)d_ws;
  size_t off = 0;
  auto carve = [&](size_t bytes)->char*{
    char* r = base + off;
    off = align256(off + bytes);
    return r;
  };
  unsigned short* featA  = (unsigned short*) carve((size_t)N*DD*sizeof(unsigned short));
  unsigned short* featB  = (unsigned short*) carve((size_t)N*DD*sizeof(unsigned short));
  // msgh (layer loop) aliases csre (setup phase A temp) -- disjoint lifetimes
  size_t shared_bytes = (size_t)N*DD*sizeof(unsigned short);
  size_t csre_bytes   = (size_t)E*sizeof(int2);
  unsigned short* msgh   = (unsigned short*) carve(shared_bytes > csre_bytes ? shared_bytes : csre_bytes);
  int2*           csre   = (int2*)msgh;
  unsigned short* wb     = (unsigned short*) carve((size_t)LYR*DD*K2*sizeof(unsigned short));
  float*          nscale = (float*)          carve((size_t)N*sizeof(float));
  int*            rowptr = (int*)            carve((size_t)(N+1)*sizeof(int));
  int*            deg    = (int*)            carve((size_t)N*sizeof(int));
  int*            bcur   = (int*)            carve((size_t)NBMAX*sizeof(int));
  int*            csum   = (int*)            carve(4096);
  int2*           csre2  = (int2*)           carve(((size_t)E + 7*(size_t)N + 8)*sizeof(int2));
  (void)ws_size; (void)n_in; (void)out_size;

  const int C  = (N + 1023)/1024;
  const int NB = (N + 127)/128;

  // CSR build (padded rowptr) + binned fill + packs
  zero_i32_kernel<<<(N + 255)/256, 256, 0, stream>>>(deg, N);
  degree_kernel<<<(E + 255)/256, 256, 0, stream>>>(edge_index, E, deg);
  chunk_sum_kernel<<<C, 256, 0, stream>>>(deg, N, csum);
  chunk_scan_kernel<<<1, 64, 0, stream>>>(csum, C, rowptr + N);
  scan_within_kernel<<<C, 256, 0, stream>>>(deg, N, csum, rowptr);
  bcur_init_kernel<<<(NB + 255)/256, 256, 0, stream>>>(rowptr, bcur, NB, N);
  fill_binned_kernel<<<(E + 4095)/4096, 256, 0, stream>>>(edge_index, ew, E, bcur, csre, NB);
  sortbkt_kernel<<<NB, 256, 0, stream>>>(rowptr, bcur, csre, csre2, N);
  pack_wb_kernel<<<(LYR*DD*K2 + 255)/256, 256, 0, stream>>>(gcw, biw, wb, LYR);
  cvt_bf16_kernel<<<((N*DD/2) + 255)/256, 256, 0, stream>>>(emb, (unsigned int*)featA, N*DD/2);

  // stage 0: raw emb dot (bf16 copy)
  {
    int blocks = (int)(((size_t)Q*64 + 255)/256);
    score_kernel<<<blocks, 256, 0, stream>>>(eli, Q, featA, (const float*)nullptr, out, 0);
  }

  unsigned short* cursrc = featA;
  unsigned short* curdst = featB;
  for (int l = 0; l < LYR; l++){
    {
      int blocks = (int)(((size_t)N*64 + 255)/256);
      gather_kernel<<<blocks, 256, 0, stream>>>(rowptr, csre2, cursrc, (unsigned int*)msgh, N);
    }
    transform_mfma_kernel<<<(N + 63)/64, 128, 0, stream>>>(
        cursrc, msgh, wb + (size_t)l*DD*K2, gcb + (size_t)l*DD, bib + (size_t)l*DD,
        curdst, nscale, N);
    {
      int blocks = (int)(((size_t)Q*64 + 255)/256);
      score_kernel<<<blocks, 256, 0, stream>>>(eli, Q, curdst, nscale, out, 1);
    }
    unsigned short* tmp = cursrc; cursrc = curdst; curdst = tmp;
  }
}

// Round 7
// 623.185 us; speedup vs baseline: 1.4536x; 1.0785x over previous
//
#include <hip/hip_runtime.h>

#define DD 128
#define K2 256     // concatenated K: [msg | ego*msg]
#define NBMAX 1024 // max bucket count (N/128)
#define COLMASK 0x01FFFFFF

typedef short short8 __attribute__((ext_vector_type(8)));
typedef float f32x4  __attribute__((ext_vector_type(4)));

static inline size_t align256(size_t x){ return (x + 255) & ~(size_t)255; }

__device__ __forceinline__ unsigned short f2bf(float x){
  unsigned int u = __builtin_bit_cast(unsigned int, x);
  u += 0x7fff + ((u >> 16) & 1);          // RNE fp32 -> bf16
  return (unsigned short)(u >> 16);
}
__device__ __forceinline__ float bf2f(unsigned short h){
  unsigned int u = ((unsigned int)h) << 16;
  return __builtin_bit_cast(float, u);
}

// ---------------- utility ----------------
__global__ void zero_i32_kernel(int* __restrict__ p, int n){
  int i = blockIdx.x*blockDim.x + threadIdx.x;
  if (i < n) p[i] = 0;
}

// emb fp32 -> bf16 (packed 2/uint)
__global__ void cvt_bf16_kernel(const float* __restrict__ src, unsigned int* __restrict__ dst, int n2){
  int i = blockIdx.x*blockDim.x + threadIdx.x;
  if (i < n2){
    float2 v = *(const float2*)(src + (size_t)i*2);
    dst[i] = (unsigned int)f2bf(v.x) | ((unsigned int)f2bf(v.y) << 16);
  }
}

// ---------------- bucket histogram: LDS hist -> few global atomics ----------------
__global__ __launch_bounds__(256) void bucket_hist_kernel(
    const int* __restrict__ ei, int E, int* __restrict__ bcnt, int NB){
  __shared__ int lh[NBMAX];
  int t = threadIdx.x;
  int base = blockIdx.x * 8192;
  for (int j = t; j < NB; j += 256) lh[j] = 0;
  __syncthreads();
#pragma unroll
  for (int i = 0; i < 32; i++){
    int e = base + i*256 + t;
    if (e < E) atomicAdd(&lh[ei[e] >> 7], 1);
  }
  __syncthreads();
  for (int j = t; j < NB; j += 256){
    int c = lh[j];
    if (c) atomicAdd(&bcnt[j], c);
  }
}

// ---------------- bucket scan: bbase = excl scan(bcnt); bcur = bbase ----------------
__global__ __launch_bounds__(1024) void bucket_scan_kernel(
    const int* __restrict__ bcnt, int* __restrict__ bbase, int* __restrict__ bcur, int NB){
  __shared__ int a[NBMAX], btmp[NBMAX];
  int t = threadIdx.x;
  a[t] = (t < NB) ? bcnt[t] : 0;
  __syncthreads();
  int* src = a; int* dst = btmp;
  for (int o = 1; o < 1024; o <<= 1){
    int val = src[t];
    if (t >= o) val += src[t - o];
    dst[t] = val;
    __syncthreads();
    int* tm = src; src = dst; dst = tm;
  }
  int excl = (t == 0) ? 0 : src[t-1];
  if (t < NB){ bbase[t] = excl; bcur[t] = excl; }
}

// ---------------- binned fill, phase A: append into raw bucket regions ----------------
__global__ __launch_bounds__(256) void fill_binned_kernel(
    const int* __restrict__ ei, const float* __restrict__ ew, int E,
    int* __restrict__ bcur, int2* __restrict__ csre, int NB){
  __shared__ int lhist[NBMAX];
  __shared__ int lbase[NBMAX];
  int t = threadIdx.x;
  int base = blockIdx.x * 4096;
  for (int j = t; j < NB; j += 256) lhist[j] = 0;
  __syncthreads();
  int rows[16];
#pragma unroll
  for (int i = 0; i < 16; i++){
    int e = base + i*256 + t;
    int r = (e < E) ? ei[e] : -1;
    rows[i] = r;
    if (r >= 0) atomicAdd(&lhist[r >> 7], 1);
  }
  __syncthreads();
  for (int j = t; j < NB; j += 256){
    int c = lhist[j];
    lbase[j] = c ? atomicAdd(&bcur[j], c) : 0;
    lhist[j] = 0;                     // reuse as local cursor
  }
  __syncthreads();
#pragma unroll
  for (int i = 0; i < 16; i++){
    int e = base + i*256 + t;
    int r = rows[i];
    if (r >= 0){
      int b = r >> 7;
      int pos = lbase[b] + atomicAdd(&lhist[b], 1);
      int col = ei[E + e];
      float w = ew[e];
      csre[pos] = make_int2(((r & 127) << 25) | col, __float_as_int(w));
    }
  }
}

// ---------------- per-bucket row degrees (coalesced deg write, no global atomics) ----------
__global__ __launch_bounds__(256) void bucket_rowdeg_kernel(
    const int* __restrict__ bbase, const int* __restrict__ bcur,
    const int2* __restrict__ csre, int* __restrict__ deg, int N){
  __shared__ int lc[128];
  int b = blockIdx.x, t = threadIdx.x;
  if (t < 128) lc[t] = 0;
  __syncthreads();
  int beg = bbase[b], end = bcur[b];
  for (int i = beg + t; i < end; i += 256)
    atomicAdd(&lc[((unsigned int)csre[i].x) >> 25], 1);
  __syncthreads();
  int gr = b*128 + t;
  if (t < 128 && gr < N) deg[gr] = lc[t];
}

// ---------------- PADDED rowptr scan (rows padded to x8) ----------------
__global__ void chunk_sum_kernel(const int* __restrict__ deg, int N, int* __restrict__ csum){
  __shared__ int sh[256];
  int t = threadIdx.x;
  int base = blockIdx.x*1024;
  int s = 0;
  for (int i = t; i < 1024; i += 256){
    int idx = base + i;
    if (idx < N) s += (deg[idx] + 7) & ~7;      // padded degree
  }
  sh[t] = s; __syncthreads();
  for (int o = 128; o > 0; o >>= 1){
    if (t < o) sh[t] += sh[t+o];
    __syncthreads();
  }
  if (t == 0) csum[blockIdx.x] = sh[0];
}

__global__ void chunk_scan_kernel(int* __restrict__ csum, int C, int* __restrict__ total){
  if (blockIdx.x == 0 && threadIdx.x == 0){
    int run = 0;
    for (int i = 0; i < C; i++){ int v = csum[i]; csum[i] = run; run += v; }
    *total = run;
  }
}

__global__ void scan_within_kernel(const int* __restrict__ deg, int N,
                                   const int* __restrict__ csum, int* __restrict__ rowptr){
  __shared__ int a[256], b[256];
  int t = threadIdx.x;
  int base = blockIdx.x*1024 + t*4;
  int v[4]; int s = 0;
#pragma unroll
  for (int i = 0; i < 4; i++){
    int idx = base + i;
    int d = (idx < N) ? ((deg[idx] + 7) & ~7) : 0;   // padded degree
    v[i] = s; s += d;
  }
  a[t] = s; __syncthreads();
  int* src = a; int* dst = b;
  for (int o = 1; o < 256; o <<= 1){
    int val = src[t];
    if (t >= o) val += src[t - o];
    dst[t] = val;
    __syncthreads();
    int* tmp = src; src = dst; dst = tmp;
  }
  int excl = (t == 0) ? 0 : src[t-1];
  int off = csum[blockIdx.x] + excl;
#pragma unroll
  for (int i = 0; i < 4; i++){
    int idx = base + i;
    if (idx < N) rowptr[idx] = off + v[i];
  }
}

// ---------------- binned fill, phase B: rank by row within bucket -> padded CSR ----------------
// Reads raw bucket region [bbase[b], bcur[b]); writes each edge to its padded CSR slot;
// pads [rowptr[r]+deg, rowptr[r+1]) with (col=r, w=0) so gather is tail-free.
__global__ __launch_bounds__(256) void sortbkt_kernel(
    const int* __restrict__ rowptr, const int* __restrict__ bbase, const int* __restrict__ bcur,
    const int2* __restrict__ csre, int2* __restrict__ csre2, int N){
  __shared__ int lrp[129];
  __shared__ int lcur[128];
  int b = blockIdx.x;
  int t = threadIdx.x;
  int r0 = b*128;
  for (int j = t; j < 129; j += 256){
    int rr = r0 + j; if (rr > N) rr = N;
    lrp[j] = rowptr[rr];
  }
  if (t < 128) lcur[t] = 0;
  __syncthreads();
  int beg = bbase[b], bend = bcur[b];
  for (int i = beg + t; i < bend; i += 256){
    int2 e = csre[i];
    int rl = ((unsigned int)e.x) >> 25;
    int pos = lrp[rl] + atomicAdd(&lcur[rl], 1);
    csre2[pos] = e;                   // scattered only within ~16 KB window
  }
  __syncthreads();
  if (t < 128 && r0 + t < N){
    int pbeg = lrp[t] + lcur[t];      // after real edges
    int pend = lrp[t+1];              // padded row end
    int2 pad = make_int2(r0 + t, 0);  // w = 0 -> contributes nothing
    for (int i = pbeg; i < pend; i++) csre2[i] = pad;
  }
}

// ---------------- weight pack: wb[l][n][k2] bf16 ----------------
__global__ void pack_wb_kernel(const float* __restrict__ gcw, const float* __restrict__ biw,
                               unsigned short* __restrict__ wb, int LYR){
  int i = blockIdx.x*blockDim.x + threadIdx.x;
  int total = LYR*DD*K2;
  if (i >= total) return;
  int l = i / (DD*K2);
  int r = i - l*(DD*K2);
  int n = r >> 8;
  int k = r & (K2-1);
  float v = (k < DD) ? gcw[(size_t)l*DD*DD + n*DD + k]
                     : biw[(size_t)l*DD*DD + n*DD + (k - DD)];
  wb[i] = f2bf(v);
}

// ---------------- gather: msgh[n] = bf16( sum_e w*egoh[col] ), tail-free (rows padded x8) ----
__global__ void gather_kernel(const int* __restrict__ rowptr, const int2* __restrict__ csre,
                              const unsigned short* __restrict__ egoh,
                              unsigned int* __restrict__ msgh, int N){
  int wid = (int)(((size_t)blockIdx.x*blockDim.x + threadIdx.x) >> 6);
  int lane = threadIdx.x & 63;
  if (wid >= N) return;
  int beg = rowptr[wid], end = rowptr[wid+1];
  float ax = 0.f, ay = 0.f;
  for (int k = beg; k < end; k += 8){   // always full batches of 8
    int2 e[8]; unsigned int v[8];
#pragma unroll
    for (int u = 0; u < 8; u++) e[u] = csre[k+u];
#pragma unroll
    for (int u = 0; u < 8; u++)
      v[u] = *(const unsigned int*)(egoh + (size_t)(e[u].x & COLMASK)*DD + lane*2);
#pragma unroll
    for (int u = 0; u < 8; u++){
      float w = __int_as_float(e[u].y);
      ax = fmaf(w, bf2f((unsigned short)v[u]), ax);
      ay = fmaf(w, bf2f((unsigned short)(v[u]>>16)), ay);
    }
  }
  msgh[(size_t)wid*(DD/2) + lane] = (unsigned int)f2bf(ax) | ((unsigned int)f2bf(ay) << 16);
}

// ---------------- transform (bf16 MFMA, K=256 concat GEMM), all-bf16 I/O ----------------
__global__ __launch_bounds__(128) void transform_mfma_kernel(
    const unsigned short* __restrict__ egoh_in, const unsigned short* __restrict__ msgh,
    const unsigned short* __restrict__ wb, const float* __restrict__ gcb,
    const float* __restrict__ bib, unsigned short* __restrict__ egoh_out,
    float* __restrict__ nscale, int N){
  __shared__ unsigned short As[64*264];
  __shared__ float Bias[DD];
  int t = threadIdx.x;
  int r0 = blockIdx.x * 64;
  if (t < DD) Bias[t] = gcb[t] + bib[t];

#pragma unroll
  for (int it = 0; it < 8; it++){
    int i = it*128 + t;
    int r = i >> 4, c = (i & 15);
    int gr = r0 + r;
    uint4 m4 = make_uint4(0,0,0,0), e4 = make_uint4(0,0,0,0);
    if (gr < N){
      m4 = *(const uint4*)(msgh    + (size_t)gr*DD + c*8);
      e4 = *(const uint4*)(egoh_in + (size_t)gr*DD + c*8);
    }
    *(uint4*)&As[r*264 + c*8] = m4;
    unsigned int p[4];
    unsigned int me[4] = {m4.x, m4.y, m4.z, m4.w};
    unsigned int ee[4] = {e4.x, e4.y, e4.z, e4.w};
#pragma unroll
    for (int u = 0; u < 4; u++){
      float px = bf2f((unsigned short)me[u]) * bf2f((unsigned short)ee[u]);
      float py = bf2f((unsigned short)(me[u]>>16)) * bf2f((unsigned short)(ee[u]>>16));
      p[u] = (unsigned int)f2bf(px) | ((unsigned int)f2bf(py) << 16);
    }
    *(uint4*)&As[r*264 + DD + c*8] = make_uint4(p[0],p[1],p[2],p[3]);
  }
  __syncthreads();

  int wave = t >> 6, lane = t & 63;
  int m = lane & 15, q = lane >> 4;
  int wr0 = wave * 32;

  f32x4 acc[8][2];
#pragma unroll
  for (int ct = 0; ct < 8; ct++){ acc[ct][0] = (f32x4)0.f; acc[ct][1] = (f32x4)0.f; }

#pragma unroll
  for (int kc = 0; kc < 8; kc++){
    int koff = kc*32 + q*8;
    short8 a0 = *(const short8*)&As[(wr0 + m)*264 + koff];
    short8 a1 = *(const short8*)&As[(wr0 + 16 + m)*264 + koff];
#pragma unroll
    for (int ct = 0; ct < 8; ct++){
      short8 b = *(const short8*)&wb[(size_t)(ct*16 + m)*K2 + koff];
      acc[ct][0] = __builtin_amdgcn_mfma_f32_16x16x32_bf16(a0, b, acc[ct][0], 0, 0, 0);
      acc[ct][1] = __builtin_amdgcn_mfma_f32_16x16x32_bf16(a1, b, acc[ct][1], 0, 0, 0);
    }
  }

#pragma unroll
  for (int rt = 0; rt < 2; rt++){
#pragma unroll
    for (int reg = 0; reg < 4; reg++){
      int gr = r0 + wr0 + rt*16 + q*4 + reg;
      float rs = 0.f;
#pragma unroll
      for (int ct = 0; ct < 8; ct++){
        float x = acc[ct][rt][reg] + Bias[ct*16 + m];
        x = (x > 0.f) ? x : 0.2f*x;
        rs += x*x;
        if (gr < N) egoh_out[(size_t)gr*DD + ct*16 + m] = f2bf(x);
      }
#pragma unroll
      for (int o = 1; o < 16; o <<= 1) rs += __shfl_xor(rs, o, 16);
      if (m == 0 && gr < N)
        nscale[gr] = 1.0f / fmaxf(sqrtf(rs), 1e-12f);
    }
  }
}

// ---------------- score ----------------
__global__ void score_kernel(const int* __restrict__ eli, int Q,
                             const unsigned short* __restrict__ feath,
                             const float* __restrict__ nscale,
                             float* __restrict__ out, int accumulate){
  int wid = (int)(((size_t)blockIdx.x*blockDim.x + threadIdx.x) >> 6);
  int lane = threadIdx.x & 63;
  if (wid >= Q) return;
  int s = eli[wid];
  int d = eli[Q + wid];
  unsigned int a = *(const unsigned int*)(feath + (size_t)s*DD + lane*2);
  unsigned int b = *(const unsigned int*)(feath + (size_t)d*DD + lane*2);
  float p = bf2f((unsigned short)a)*bf2f((unsigned short)b)
          + bf2f((unsigned short)(a>>16))*bf2f((unsigned short)(b>>16));
  for (int o = 32; o > 0; o >>= 1) p += __shfl_xor(p, o, 64);
  if (lane == 0){
    if (nscale) p *= nscale[s]*nscale[d];
    if (accumulate) out[wid] += p;
    else            out[wid]  = p;
  }
}

extern "C" void kernel_launch(void* const* d_in, const int* in_sizes, int n_in,
                              void* d_out, int out_size, void* d_ws, size_t ws_size,
                              hipStream_t stream){
  const int*   edge_index = (const int*)d_in[0];
  const int*   eli        = (const int*)d_in[1];
  const float* ew         = (const float*)d_in[2];
  const float* emb        = (const float*)d_in[3];
  const float* gcw        = (const float*)d_in[4];
  const float* gcb        = (const float*)d_in[5];
  const float* biw        = (const float*)d_in[6];
  const float* bib        = (const float*)d_in[7];
  const int E   = in_sizes[2];
  const int Q   = in_sizes[1] / 2;
  const int N   = in_sizes[3] / DD;
  const int LYR = in_sizes[4] / (DD*DD);
  float* out = (float*)d_out;

  char* base = (char*)d_ws;
  size_t off = 0;
  auto carve = [&](size_t bytes)->char*{
    char* r = base + off;
    off = align256(off + bytes);
    return r;
  };
  unsigned short* featA  = (unsigned short*) carve((size_t)N*DD*sizeof(unsigned short));
  unsigned short* featB  = (unsigned short*) carve((size_t)N*DD*sizeof(unsigned short));
  // msgh (layer loop) aliases csre (setup phase A temp) -- disjoint lifetimes
  size_t shared_bytes = (size_t)N*DD*sizeof(unsigned short);
  size_t csre_bytes   = (size_t)E*sizeof(int2);
  unsigned short* msgh   = (unsigned short*) carve(shared_bytes > csre_bytes ? shared_bytes : csre_bytes);
  int2*           csre   = (int2*)msgh;
  unsigned short* wb     = (unsigned short*) carve((size_t)LYR*DD*K2*sizeof(unsigned short));
  float*          nscale = (float*)          carve((size_t)N*sizeof(float));
  int*            rowptr = (int*)            carve((size_t)(N+1)*sizeof(int));
  int*            deg    = (int*)            carve((size_t)N*sizeof(int));
  int*            bcnt   = (int*)            carve((size_t)NBMAX*sizeof(int));
  int*            bbase  = (int*)            carve((size_t)NBMAX*sizeof(int));
  int*            bcur   = (int*)            carve((size_t)NBMAX*sizeof(int));
  int*            csum   = (int*)            carve(4096);
  int2*           csre2  = (int2*)           carve(((size_t)E + 7*(size_t)N + 8)*sizeof(int2));
  (void)ws_size; (void)n_in; (void)out_size;

  const int C  = (N + 1023)/1024;
  const int NB = (N + 127)/128;

  // CSR build: bucket hist -> scan -> raw binned fill -> row degrees -> padded rowptr -> sort+pad
  zero_i32_kernel<<<(NB + 255)/256, 256, 0, stream>>>(bcnt, NB);
  bucket_hist_kernel<<<(E + 8191)/8192, 256, 0, stream>>>(edge_index, E, bcnt, NB);
  bucket_scan_kernel<<<1, 1024, 0, stream>>>(bcnt, bbase, bcur, NB);
  fill_binned_kernel<<<(E + 4095)/4096, 256, 0, stream>>>(edge_index, ew, E, bcur, csre, NB);
  bucket_rowdeg_kernel<<<NB, 256, 0, stream>>>(bbase, bcur, csre, deg, N);
  chunk_sum_kernel<<<C, 256, 0, stream>>>(deg, N, csum);
  chunk_scan_kernel<<<1, 64, 0, stream>>>(csum, C, rowptr + N);
  scan_within_kernel<<<C, 256, 0, stream>>>(deg, N, csum, rowptr);
  sortbkt_kernel<<<NB, 256, 0, stream>>>(rowptr, bbase, bcur, csre, csre2, N);
  pack_wb_kernel<<<(LYR*DD*K2 + 255)/256, 256, 0, stream>>>(gcw, biw, wb, LYR);
  cvt_bf16_kernel<<<((N*DD/2) + 255)/256, 256, 0, stream>>>(emb, (unsigned int*)featA, N*DD/2);

  // stage 0: raw emb dot (bf16 copy)
  {
    int blocks = (int)(((size_t)Q*64 + 255)/256);
    score_kernel<<<blocks, 256, 0, stream>>>(eli, Q, featA, (const float*)nullptr, out, 0);
  }

  unsigned short* cursrc = featA;
  unsigned short* curdst = featB;
  for (int l = 0; l < LYR; l++){
    {
      int blocks = (int)(((size_t)N*64 + 255)/256);
      gather_kernel<<<blocks, 256, 0, stream>>>(rowptr, csre2, cursrc, (unsigned int*)msgh, N);
    }
    transform_mfma_kernel<<<(N + 63)/64, 128, 0, stream>>>(
        cursrc, msgh, wb + (size_t)l*DD*K2, gcb + (size_t)l*DD, bib + (size_t)l*DD,
        curdst, nscale, N);
    {
      int blocks = (int)(((size_t)Q*64 + 255)/256);
      score_kernel<<<blocks, 256, 0, stream>>>(eli, Q, curdst, nscale, out, 1);
    }
    unsigned short* tmp = cursrc; cursrc = curdst; curdst = tmp;
  }
}